// Round 1
// baseline (187.859 us; speedup 1.0000x reference)
//
#include <hip/hip_runtime.h>

#define NB    128
#define NT    8192
#define TPB   256
#define CHUNK 32

// XOR swizzle: flips bits [2:4] of the element index with the low 3 bits of
// the 32-element-row index. Keeps float4 groups contiguous & 16B aligned,
// makes both access patterns (coalesced k*1024+tid*4 and per-thread
// contiguous chunk tid*32+4j) <=2-way bank conflicts (free on wave64).
__device__ __forceinline__ int swz(int n) { return n ^ (((n >> 5) & 7) << 2); }

__global__ __launch_bounds__(TPB, 4) void mrpcen_kernel(
    const float* __restrict__ x,
    const float* __restrict__ log_alpha,
    const float* __restrict__ log_delta,
    const float* __restrict__ log_r,
    float* __restrict__ out)
{
    __shared__ __align__(16) float sh[NT];     // 32 KiB: x staging, then output staging
    __shared__ float4 sB4[TPB];                // 4 KiB: block scan of B offsets

    const int tid = threadIdx.x;
    const int bf  = blockIdx.x;        // 0..1023
    const int b   = bf >> 7;
    const int f   = bf & (NB - 1);

    const float* xrow = x + (size_t)bf * NT;

    // per-band params (params are stored in log space)
    const float alpha  = __expf(log_alpha[f]);
    const float r      = __expf(log_r[f]);
    const float delta  = __expf(log_delta[f]);
    const float deltar = __expf(r * log_delta[f]);   // delta^r, exact from log param

    // smoothing coefficients s_t = (sqrt(1+4t^2)-1)/(2t^2), A_t = (1-s)^32
    float s[4], A[4];
    const float tv[4] = {2.f, 8.f, 32.f, 128.f};
#pragma unroll
    for (int t = 0; t < 4; t++) {
        float t2 = tv[t] * tv[t];
        s[t] = (sqrtf(1.f + 4.f * t2) - 1.f) / (2.f * t2);
        float a1 = 1.f - s[t];
        float a = a1 * a1; a = a * a; a = a * a; a = a * a; a = a * a; // (1-s)^32
        A[t] = a;
    }

    // ---- 1. coalesced global -> LDS (swizzled) ----
#pragma unroll
    for (int k = 0; k < 8; k++) {
        int n = k * 1024 + tid * 4;
        float4 v = *reinterpret_cast<const float4*>(xrow + n);
        *reinterpret_cast<float4*>(&sh[swz(n)]) = v;
    }
    __syncthreads();

    const float x0 = sh[0];   // swz(0)==0; scan carry init m[-1] = x[0] (broadcast)

    // ---- 2. own contiguous chunk into registers ----
    float xc[CHUNK];
#pragma unroll
    for (int j = 0; j < 8; j++) {
        int n = tid * CHUNK + 4 * j;
        float4 v = *reinterpret_cast<const float4*>(&sh[swz(n)]);
        xc[4 * j + 0] = v.x; xc[4 * j + 1] = v.y;
        xc[4 * j + 2] = v.z; xc[4 * j + 3] = v.w;
    }

    // ---- 3. local affine compose for all 4 rates (B with m_in = 0) ----
    float Bl[4] = {0.f, 0.f, 0.f, 0.f};
#pragma unroll
    for (int i = 0; i < CHUNK; i++) {
        float xi = xc[i];
#pragma unroll
        for (int t = 0; t < 4; t++)
            Bl[t] = s[t] * xi + (1.f - s[t]) * Bl[t];
    }

    // ---- 4. block scan: S[i] = B[i] + A*S[i-1]  (A uniform per t) ----
    sB4[tid] = make_float4(Bl[0], Bl[1], Bl[2], Bl[3]);
    float ap0 = A[0], ap1 = A[1], ap2 = A[2], ap3 = A[3];
    for (int d = 1; d < TPB; d <<= 1) {
        __syncthreads();
        float4 cur = sB4[tid];
        float4 prev = make_float4(0.f, 0.f, 0.f, 0.f);
        if (tid >= d) prev = sB4[tid - d];
        __syncthreads();
        if (tid >= d) {
            cur.x += ap0 * prev.x;
            cur.y += ap1 * prev.y;
            cur.z += ap2 * prev.z;
            cur.w += ap3 * prev.w;
            sB4[tid] = cur;
        }
        ap0 *= ap0; ap1 *= ap1; ap2 *= ap2; ap3 *= ap3;
    }
    __syncthreads();
    float4 Sp = (tid > 0) ? sB4[tid - 1] : make_float4(0.f, 0.f, 0.f, 0.f);
    const float Sprev[4] = {Sp.x, Sp.y, Sp.z, Sp.w};

    // incoming m for this chunk: m_in = A^tid * x0 + Sprev  (binary powering)
    float m_in[4];
#pragma unroll
    for (int t = 0; t < 4; t++) {
        float p = 1.f, base = A[t];
        int e = tid;
#pragma unroll
        for (int bit = 0; bit < 8; bit++) {
            if (e & 1) p *= base;
            base *= base;
            e >>= 1;
        }
        m_in[t] = p * x0 + Sprev[t];
    }

    // ---- 5. per rate: recurrence + epilogue in regs, stage in sh, coalesced store ----
    for (int t = 0; t < 4; t++) {
        const float st = s[t], a1 = 1.f - s[t];
        float m = m_in[t];
        // stage writes hit only this thread's own region of sh -> no barrier needed
#pragma unroll
        for (int j = 0; j < 8; j++) {
            float ov[4];
#pragma unroll
            for (int q = 0; q < 4; q++) {
                float xi = xc[4 * j + q];
                m = st * xi + a1 * m;
                // smooth = (eps + m)^(-alpha)
                float smooth = __expf(-alpha * __logf(1e-5f + m));
                // pcen = (x*smooth + delta)^r - delta^r   (arg >= delta = 10 > 0)
                ov[q] = __expf(r * __logf(xi * smooth + delta)) - deltar;
            }
            float4 o = make_float4(ov[0], ov[1], ov[2], ov[3]);
            *reinterpret_cast<float4*>(&sh[swz(tid * CHUNK + 4 * j)]) = o;
        }
        __syncthreads();
        float* oplane = out + (((size_t)b * 4 + t) * NB + f) * (size_t)NT;
#pragma unroll
        for (int k = 0; k < 8; k++) {
            int n = k * 1024 + tid * 4;
            float4 v = *reinterpret_cast<const float4*>(&sh[swz(n)]);
            *reinterpret_cast<float4*>(oplane + n) = v;
        }
        __syncthreads();   // before next t overwrites the stage
    }
}

extern "C" void kernel_launch(void* const* d_in, const int* in_sizes, int n_in,
                              void* d_out, int out_size, void* d_ws, size_t ws_size,
                              hipStream_t stream) {
    const float* x         = (const float*)d_in[0];
    const float* log_alpha = (const float*)d_in[1];
    const float* log_delta = (const float*)d_in[2];
    const float* log_r     = (const float*)d_in[3];
    float* out = (float*)d_out;

    // one block per (b, f) row: 8 * 128 = 1024 blocks
    mrpcen_kernel<<<dim3(8 * NB), dim3(TPB), 0, stream>>>(
        x, log_alpha, log_delta, log_r, out);
}